// Round 16
// baseline (180.204 us; speedup 1.0000x reference)
//
#include <hip/hip_runtime.h>

#define NN 4096
#define DD 512
#define EE 64
#define HH 8

typedef _Float16 f16;
typedef f16 f16x2 __attribute__((ext_vector_type(2)));
typedef f16 f16x4 __attribute__((ext_vector_type(4)));
typedef f16 f16x8 __attribute__((ext_vector_type(8)));
typedef float f32x4 __attribute__((ext_vector_type(4)));
typedef __fp16 fp16x2 __attribute__((ext_vector_type(2)));

// hardware exp2 (v_exp_f32). NOTE: __exp2f collides with glibc math.h macros.
__device__ __forceinline__ float hexp2(float x) { return __builtin_amdgcn_exp2f(x); }
// packed f32x2 -> f16x2 (v_cvt_pkrtz_f16_f32); bit-cast fixes __fp16/_Float16 vec mismatch
__device__ __forceinline__ f16x2 pkrtz(float a, float b) {
    fp16x2 r = __builtin_amdgcn_cvt_pkrtz(a, b);
    return __builtin_bit_cast(f16x2, r);
}
// NOTE: clang forbids &vec[i] on ext_vector types — compose via unions.
union f16x4u { f16x4 v4; f16x2 v2[2]; };
union f16x8u { f16x8 v8; f16x2 v2[4]; };
union f32x8u { float a[8]; f32x4 v[2]; };

// ---------------- fused prep: converts + weight transposes, 1 launch ----------------
__device__ void tile_transpose_cvt(const float* __restrict__ src, f16* __restrict__ dst,
                                   int R, int C, int bx, int by, int tid)
{
    __shared__ float t[32][33];
    const int tx = tid & 31, ty = tid >> 5;
    #pragma unroll
    for (int i = 0; i < 4; ++i) {
        int r = ty + i * 8;
        t[r][tx] = src[(size_t)(by + r) * C + bx + tx];
    }
    __syncthreads();
    #pragma unroll
    for (int i = 0; i < 4; ++i) {
        int c = ty + i * 8;
        dst[(size_t)(bx + c) * R + by + tx] = (f16)t[tx][c];
    }
}

// grid (256, 6): y=0 x->f16 (8 passes), y=1 ffn_w->f16, y=2..4 wq/wk/wv transpose, y=5 w_mh transpose
__global__ __launch_bounds__(256) void prep_kernel(
    const float* __restrict__ x, const float* __restrict__ ffn_w,
    const float* __restrict__ wq, const float* __restrict__ wk, const float* __restrict__ wv,
    const float* __restrict__ w_mh,
    f16* __restrict__ xh, f16* __restrict__ ffnT, f16* __restrict__ wqkvT, f16* __restrict__ wmhT)
{
    const int job = blockIdx.y;
    const int tid = threadIdx.x;
    if (job == 0) {
        size_t i = ((size_t)blockIdx.x * 256 + tid) * 4;
        const size_t step = (size_t)256 * 256 * 4;
        for (; i < (size_t)NN * DD; i += step) {
            float4 t = *(const float4*)(x + i);
            f16x4 h = { (f16)t.x, (f16)t.y, (f16)t.z, (f16)t.w };
            *(f16x4*)(xh + i) = h;
        }
    } else if (job == 1) {
        size_t i = ((size_t)blockIdx.x * 256 + tid) * 4;   // DD*DD = 256 blocks exactly
        float4 t = *(const float4*)(ffn_w + i);
        f16x4 h = { (f16)t.x, (f16)t.y, (f16)t.z, (f16)t.w };
        *(f16x4*)(ffnT + i) = h;
    } else if (job <= 4) {
        const float* src = (job == 2) ? wq : (job == 3) ? wk : wv;
        f16* dst = wqkvT + (size_t)(job - 2) * HH * EE * DD;
        const int z = blockIdx.x >> 5;        // head 0..7
        const int tile = blockIdx.x & 31;     // 2 (E) x 16 (D)
        tile_transpose_cvt(src + (size_t)z * DD * EE, dst + (size_t)z * DD * EE,
                           DD, EE, (tile & 1) * 32, (tile >> 1) * 32, tid);
    } else {
        const int tile = blockIdx.x;          // 16 x 16
        tile_transpose_cvt(w_mh, wmhT, DD, DD, (tile & 15) * 32, (tile >> 4) * 32, tid);
    }
}

// ---------------- QKV GEMM via MFMA: C[64n x 64col], K=512, LDS double-buffered ----------------
__global__ __launch_bounds__(256) void qkv_mfma_kernel(
    const f16* __restrict__ A, const f16* __restrict__ BT,
    f16* __restrict__ qh, f16* __restrict__ kh, f16* __restrict__ vTh)
{
    __shared__ f16 As[2][64][72];
    __shared__ f16 Bs[2][64][72];
    const int tid = threadIdx.x;
    const int n0 = blockIdx.x * 64;
    const int cb = blockIdx.y;
    const int sel = cb >> 3, h = cb & 7;
    const f16* Arow = A + (size_t)n0 * DD;
    const f16* Brow = BT + (size_t)cb * 64 * DD;

    const int lane = tid & 63, wave = tid >> 6;
    const int l16 = lane & 15, quad = lane >> 4;
    const int m0 = wave * 16;

    const int r1 = tid >> 3, c1 = (tid & 7) * 8;
    const int r2 = (tid + 256) >> 3, c2 = ((tid + 256) & 7) * 8;

    f32x4 acc[4];
    #pragma unroll
    for (int t = 0; t < 4; ++t) acc[t] = (f32x4){0.f, 0.f, 0.f, 0.f};

    f16x8 a1 = *(const f16x8*)(Arow + (size_t)r1 * DD + c1);
    f16x8 a2 = *(const f16x8*)(Arow + (size_t)r2 * DD + c2);
    f16x8 b1 = *(const f16x8*)(Brow + (size_t)r1 * DD + c1);
    f16x8 b2 = *(const f16x8*)(Brow + (size_t)r2 * DD + c2);

    int buf = 0;
    for (int kt = 0; kt < DD; kt += 64) {
        *(f16x8*)(&As[buf][r1][c1]) = a1;
        *(f16x8*)(&As[buf][r2][c2]) = a2;
        *(f16x8*)(&Bs[buf][r1][c1]) = b1;
        *(f16x8*)(&Bs[buf][r2][c2]) = b2;
        __syncthreads();
        if (kt + 64 < DD) {
            a1 = *(const f16x8*)(Arow + (size_t)r1 * DD + kt + 64 + c1);
            a2 = *(const f16x8*)(Arow + (size_t)r2 * DD + kt + 64 + c2);
            b1 = *(const f16x8*)(Brow + (size_t)r1 * DD + kt + 64 + c1);
            b2 = *(const f16x8*)(Brow + (size_t)r2 * DD + kt + 64 + c2);
        }
        #pragma unroll
        for (int kk = 0; kk < 64; kk += 32) {
            f16x8 a = *(const f16x8*)(&As[buf][m0 + l16][kk + quad * 8]);
            #pragma unroll
            for (int t = 0; t < 4; ++t) {
                f16x8 b = *(const f16x8*)(&Bs[buf][t * 16 + l16][kk + quad * 8]);
                acc[t] = __builtin_amdgcn_mfma_f32_16x16x32_f16(a, b, acc[t], 0, 0, 0);
            }
        }
        buf ^= 1;
    }

    if (sel == 2) {
        #pragma unroll
        for (int t = 0; t < 4; ++t) {
            int e = t * 16 + l16;
            f16x4 v = { (f16)acc[t][0], (f16)acc[t][1], (f16)acc[t][2], (f16)acc[t][3] };
            *(f16x4*)(vTh + ((size_t)h * EE + e) * NN + n0 + m0 + quad * 4) = v;
        }
    } else {
        f16* o = (sel == 0) ? qh : kh;
        // q: bake 1/sqrt(E) * log2(e) so attention can use raw v_exp_f32 (exp2)
        const float s = (sel == 0) ? 0.125f * 1.44269504088896f : 1.0f;
        #pragma unroll
        for (int r = 0; r < 4; ++r) {
            int row = n0 + m0 + quad * 4 + r;
            #pragma unroll
            for (int t = 0; t < 4; ++t)
                o[(size_t)h * NN * EE + (size_t)row * EE + t * 16 + l16] = (f16)(acc[t][r] * s);
        }
    }
}

// ---------------- Flash attention v10: BQ=256 (4 q-strips/wave) ----------------
// r15 falsified the global-latency theory (FETCH 6x down, dur flat); arithmetic says the
// LDS pipe (~20 b128/wave-iter x 12cyc, all 4 waves reading the full Ks/VsT) is the cap.
// 4 strips/wave: each K/V frag read feeds 4 MFMAs -> total LDS instr halves.
#define BQ 256
#define NSTRIP 4
#define BK 64
#define LK (BK + 12)   // 76 halfs: frag-read row bank-step 6 mod 32 -> conflict-free

__global__ __launch_bounds__(256) void attn_mfma_kernel(
    const f16* __restrict__ q, const f16* __restrict__ k,
    const f16* __restrict__ vT, f16* __restrict__ Opart, float* __restrict__ lpart)
{
    __shared__ f16 Ks[BK][LK];    // permuted key rows
    __shared__ f16 VsT[EE][LK];   // [e][key]

    const int tid = threadIdx.x;
    const int h = blockIdx.x;               // XCD-locality dim
    const int n0 = blockIdx.y * BQ;
    const int sp = blockIdx.z;
    const int nsp = gridDim.z;
    const int wave = tid >> 6;
    const int lane = tid & 63;
    const int l16 = lane & 15;
    const int quad = lane >> 4;
    const int m0 = wave * 16;

    const f16* qh = q + (size_t)h * NN * EE;
    const f16* kh = k + (size_t)h * NN * EE;
    const f16* vh = vT + (size_t)h * NN * EE;  // [e][n]

    // Q B-fragments for all strips (loaded once from global)
    f16x8 qf[NSTRIP][2];
    #pragma unroll
    for (int s = 0; s < NSTRIP; ++s) {
        const f16* qb = qh + (size_t)(n0 + s * 64 + m0 + l16) * EE;
        qf[s][0] = *(const f16x8*)(qb + quad * 8);
        qf[s][1] = *(const f16x8*)(qb + 32 + quad * 8);
    }

    float lp[NSTRIP];
    f32x4 O[NSTRIP][4];
    #pragma unroll
    for (int s = 0; s < NSTRIP; ++s) {
        lp[s] = 0.f;
        #pragma unroll
        for (int t = 0; t < 4; ++t) O[s][t] = (f32x4){0.f, 0.f, 0.f, 0.f};
    }

    const int span = NN / nsp;
    const int k_begin = sp * span;
    const int k_end = k_begin + span;

    const int srow = tid >> 3, sc8 = (tid & 7) * 8;
    const int srow2 = (tid + 256) >> 3, sc82 = ((tid + 256) & 7) * 8;
    // key -> permuted LDS row: bits T,q,u,c -> T,u,q,c (verified r6)
    #define KPERM(kk_) (((kk_) & 0x23) | (((kk_) & 0x04) << 2) | (((kk_) & 0x18) >> 1))
    const int prow1 = KPERM(srow), prow2 = KPERM(srow2);

    // register prefetch of first tile
    f16x8 kr0 = *(const f16x8*)(kh + (size_t)(k_begin + srow) * EE + sc8);
    f16x8 kr1 = *(const f16x8*)(kh + (size_t)(k_begin + srow2) * EE + sc82);
    f16x8 vr0 = *(const f16x8*)(vh + (size_t)srow * NN + k_begin + sc8);
    f16x8 vr1 = *(const f16x8*)(vh + (size_t)srow2 * NN + k_begin + sc82);

    for (int kt = k_begin; kt < k_end; kt += BK) {
        __syncthreads();   // all waves done reading Ks/VsT from prev iter
        *(f16x8*)(&Ks[prow1][sc8]) = kr0;
        *(f16x8*)(&Ks[prow2][sc82]) = kr1;
        *(f16x8*)(&VsT[srow][sc8]) = vr0;
        *(f16x8*)(&VsT[srow2][sc82]) = vr1;
        __syncthreads();

        if (kt + BK < k_end) {   // prefetch next tile
            kr0 = *(const f16x8*)(kh + (size_t)(kt + BK + srow) * EE + sc8);
            kr1 = *(const f16x8*)(kh + (size_t)(kt + BK + srow2) * EE + sc82);
            vr0 = *(const f16x8*)(vh + (size_t)srow * NN + kt + BK + sc8);
            vr1 = *(const f16x8*)(vh + (size_t)srow2 * NN + kt + BK + sc82);
        }

        // S^T = K.Q^T per key-tile; each K-frag read feeds all NSTRIP q-strips
        f16x8 bf[NSTRIP][2];
        #pragma unroll
        for (int t = 0; t < 4; ++t) {
            f16x8 a0 = *(const f16x8*)(&Ks[t * 16 + l16][quad * 8]);
            f16x8 a1 = *(const f16x8*)(&Ks[t * 16 + l16][32 + quad * 8]);
            #pragma unroll
            for (int s = 0; s < NSTRIP; ++s) {
                f32x4 st = {0.f, 0.f, 0.f, 0.f};
                st = __builtin_amdgcn_mfma_f32_16x16x32_f16(a0, qf[s][0], st, 0, 0, 0);
                st = __builtin_amdgcn_mfma_f32_16x16x32_f16(a1, qf[s][1], st, 0, 0, 0);
                float p0 = hexp2(st[0]);
                float p1 = hexp2(st[1]);
                float p2 = hexp2(st[2]);
                float p3 = hexp2(st[3]);
                lp[s] += (p0 + p1) + (p2 + p3);
                f16x2* bp = (f16x2*)&bf[s][t >> 1];
                const int o2 = (t & 1) * 2;
                bp[o2 + 0] = pkrtz(p0, p1);
                bp[o2 + 1] = pkrtz(p2, p3);
            }
        }

        // O^T += V^T P^T ; each V-frag read feeds all strips
        #pragma unroll
        for (int te = 0; te < 4; ++te) {
            f16x8 v0 = *(const f16x8*)(&VsT[te * 16 + l16][quad * 8]);
            f16x8 v1 = *(const f16x8*)(&VsT[te * 16 + l16][32 + quad * 8]);
            #pragma unroll
            for (int s = 0; s < NSTRIP; ++s) {
                O[s][te] = __builtin_amdgcn_mfma_f32_16x16x32_f16(v0, bf[s][0], O[s][te], 0, 0, 0);
                O[s][te] = __builtin_amdgcn_mfma_f32_16x16x32_f16(v1, bf[s][1], O[s][te], 0, 0, 0);
            }
        }
    }

    // epilogue per strip: normalize by local l, store f16
    #pragma unroll
    for (int s = 0; s < NSTRIP; ++s) {
        float l = lp[s];
        l += __shfl_xor(l, 16);
        l += __shfl_xor(l, 32);
        const int row = n0 + s * 64 + m0 + l16;
        if (quad == 0)
            lpart[(size_t)sp * HH * NN + (size_t)h * NN + row] = l;
        const float inv = 1.f / l;
        f16* obase = Opart + ((size_t)sp * NN + row) * DD + h * EE;
        #pragma unroll
        for (int te = 0; te < 4; ++te) {
            f16x4u v;
            v.v2[0] = pkrtz(O[s][te][0] * inv, O[s][te][1] * inv);
            v.v2[1] = pkrtz(O[s][te][2] * inv, O[s][te][3] * inv);
            *(f16x4*)(obase + te * 16 + quad * 4) = v.v4;
        }
    }
}

// ---------------- GEMM1: fused split-combine in A-staging + row-stat emission ----------------
template<int NSP>
__global__ __launch_bounds__(256) void gemmz_mfma_kernel(
    const f16* __restrict__ Opart, const float* __restrict__ lpart,
    const f16* __restrict__ BT, const f16* __restrict__ resid16,
    f16* __restrict__ out, float* __restrict__ pstat)
{
    __shared__ f16 As[2][64][72];
    __shared__ f16 Bs[2][64][72];
    const int tid = threadIdx.x;
    const int n0 = blockIdx.x * 64;
    const int jb = blockIdx.y;
    const int j0 = jb * 64;
    const f16* Brow = BT + (size_t)j0 * DD;

    const int lane = tid & 63, wave = tid >> 6;
    const int l16 = lane & 15, quad = lane >> 4;
    const int m0 = wave * 16;

    const int r1 = tid >> 3, c1 = (tid & 7) * 8;
    const int r2 = (tid + 256) >> 3, c2 = ((tid + 256) & 7) * 8;

    f32x4 acc[4];
    #pragma unroll
    for (int t = 0; t < 4; ++t) acc[t] = (f32x4){0.f, 0.f, 0.f, 0.f};

    f16x8 op1[NSP], op2[NSP];
    #pragma unroll
    for (int s = 0; s < NSP; ++s) {
        op1[s] = *(const f16x8*)(Opart + ((size_t)s * NN + n0 + r1) * DD + c1);
        op2[s] = *(const f16x8*)(Opart + ((size_t)s * NN + n0 + r2) * DD + c2);
    }
    f16x8 b1 = *(const f16x8*)(Brow + (size_t)r1 * DD + c1);
    f16x8 b2 = *(const f16x8*)(Brow + (size_t)r2 * DD + c2);

    int buf = 0;
    for (int kt = 0; kt < DD; kt += 64) {
        const int h = kt >> 6;
        float lw1[NSP], lw2[NSP], s1 = 0.f, s2 = 0.f;
        #pragma unroll
        for (int s = 0; s < NSP; ++s) {
            lw1[s] = lpart[(size_t)s * HH * NN + (size_t)h * NN + n0 + r1];
            lw2[s] = lpart[(size_t)s * HH * NN + (size_t)h * NN + n0 + r2];
            s1 += lw1[s]; s2 += lw2[s];
        }
        const float i1 = 1.f / s1, i2 = 1.f / s2;
        float aw1[8], aw2[8];
        #pragma unroll
        for (int i = 0; i < 8; ++i) { aw1[i] = 0.f; aw2[i] = 0.f; }
        #pragma unroll
        for (int s = 0; s < NSP; ++s) {
            const float w1 = lw1[s] * i1, w2 = lw2[s] * i2;
            #pragma unroll
            for (int i = 0; i < 8; ++i) {
                aw1[i] += w1 * (float)op1[s][i];
                aw2[i] += w2 * (float)op2[s][i];
            }
        }
        f16x8u av1, av2;
        #pragma unroll
        for (int i = 0; i < 4; ++i) {
            av1.v2[i] = pkrtz(aw1[2 * i], aw1[2 * i + 1]);
            av2.v2[i] = pkrtz(aw2[2 * i], aw2[2 * i + 1]);
        }
        *(f16x8*)(&As[buf][r1][c1]) = av1.v8;
        *(f16x8*)(&As[buf][r2][c2]) = av2.v8;
        *(f16x8*)(&Bs[buf][r1][c1]) = b1;
        *(f16x8*)(&Bs[buf][r2][c2]) = b2;
        __syncthreads();
        if (kt + 64 < DD) {
            #pragma unroll
            for (int s = 0; s < NSP; ++s) {
                op1[s] = *(const f16x8*)(Opart + ((size_t)s * NN + n0 + r1) * DD + kt + 64 + c1);
                op2[s] = *(const f16x8*)(Opart + ((size_t)s * NN + n0 + r2) * DD + kt + 64 + c2);
            }
            b1 = *(const f16x8*)(Brow + (size_t)r1 * DD + kt + 64 + c1);
            b2 = *(const f16x8*)(Brow + (size_t)r2 * DD + kt + 64 + c2);
        }
        #pragma unroll
        for (int kk = 0; kk < 64; kk += 32) {
            f16x8 a = *(const f16x8*)(&As[buf][m0 + l16][kk + quad * 8]);
            #pragma unroll
            for (int t = 0; t < 4; ++t) {
                f16x8 b = *(const f16x8*)(&Bs[buf][t * 16 + l16][kk + quad * 8]);
                acc[t] = __builtin_amdgcn_mfma_f32_16x16x32_f16(a, b, acc[t], 0, 0, 0);
            }
        }
        buf ^= 1;
    }

    float vv[4][4];   // [r][t]
    #pragma unroll
    for (int r = 0; r < 4; ++r) {
        int row = n0 + m0 + quad * 4 + r;
        #pragma unroll
        for (int t = 0; t < 4; ++t) {
            int col = j0 + t * 16 + l16;
            float v = acc[t][r] + (float)resid16[(size_t)row * DD + col];
            vv[r][t] = v;
            out[(size_t)row * DD + col] = (f16)v;
        }
    }
    #pragma unroll
    for (int r = 0; r < 4; ++r) {
        float s = (vv[r][0] + vv[r][1]) + (vv[r][2] + vv[r][3]);
        float q = (vv[r][0] * vv[r][0] + vv[r][1] * vv[r][1])
                + (vv[r][2] * vv[r][2] + vv[r][3] * vv[r][3]);
        s += __shfl_xor(s, 1); q += __shfl_xor(q, 1);
        s += __shfl_xor(s, 2); q += __shfl_xor(q, 2);
        s += __shfl_xor(s, 4); q += __shfl_xor(q, 4);
        s += __shfl_xor(s, 8); q += __shfl_xor(q, 8);
        if (l16 == 0) {
            int row = n0 + m0 + quad * 4 + r;
            pstat[(size_t)jb * NN + row] = s;
            pstat[(size_t)(8 + jb) * NN + row] = q;
        }
    }
}

// ---------------- GEMM2 with LN1 fused into A-staging + residual epilogue ----------------
__global__ __launch_bounds__(256) void gemmln2_kernel(
    const f16* __restrict__ y16, const float* __restrict__ pstat,
    const f16* __restrict__ BT, const float* __restrict__ bias,
    const float* __restrict__ lng, const float* __restrict__ lnb,
    f16* __restrict__ out)
{
    __shared__ f16 As[2][64][72];
    __shared__ f16 Bs[2][64][72];
    const int tid = threadIdx.x;
    const int n0 = blockIdx.x * 64;
    const int j0 = blockIdx.y * 64;
    const f16* Brow = BT + (size_t)j0 * DD;

    const int lane = tid & 63, wave = tid >> 6;
    const int l16 = lane & 15, quad = lane >> 4;
    const int m0 = wave * 16;

    const int r1 = tid >> 3, c1 = (tid & 7) * 8;
    const int r2 = (tid + 256) >> 3, c2 = ((tid + 256) & 7) * 8;

    float s1 = 0.f, q1 = 0.f, s2 = 0.f, q2 = 0.f;
    #pragma unroll
    for (int jb = 0; jb < 8; ++jb) {
        s1 += pstat[(size_t)jb * NN + n0 + r1];
        q1 += pstat[(size_t)(8 + jb) * NN + n0 + r1];
        s2 += pstat[(size_t)jb * NN + n0 + r2];
        q2 += pstat[(size_t)(8 + jb) * NN + n0 + r2];
    }
    const float m1 = s1 * (1.f / DD), m2 = s2 * (1.f / DD);
    const float iv1 = rsqrtf(q1 * (1.f / DD) - m1 * m1 + 1e-5f);
    const float iv2 = rsqrtf(q2 * (1.f / DD) - m2 * m2 + 1e-5f);

    f32x4 acc[4];
    #pragma unroll
    for (int t = 0; t < 4; ++t) acc[t] = (f32x4){0.f, 0.f, 0.f, 0.f};

    f16x8 a1 = *(const f16x8*)(y16 + (size_t)(n0 + r1) * DD + c1);
    f16x8 a2 = *(const f16x8*)(y16 + (size_t)(n0 + r2) * DD + c2);
    f16x8 b1 = *(const f16x8*)(Brow + (size_t)r1 * DD + c1);
    f16x8 b2 = *(const f16x8*)(Brow + (size_t)r2 * DD + c2);

    int buf = 0;
    for (int kt = 0; kt < DD; kt += 64) {
        f32x8u gu, bu;
        gu.v[0] = *(const f32x4*)(lng + kt + c1);
        gu.v[1] = *(const f32x4*)(lng + kt + c1 + 4);
        bu.v[0] = *(const f32x4*)(lnb + kt + c1);
        bu.v[1] = *(const f32x4*)(lnb + kt + c1 + 4);
        f16x8u av1, av2;
        #pragma unroll
        for (int i = 0; i < 4; ++i) {
            float x0 = ((float)a1[2 * i]     - m1) * iv1 * gu.a[2 * i]     + bu.a[2 * i];
            float x1 = ((float)a1[2 * i + 1] - m1) * iv1 * gu.a[2 * i + 1] + bu.a[2 * i + 1];
            float y0 = ((float)a2[2 * i]     - m2) * iv2 * gu.a[2 * i]     + bu.a[2 * i];
            float y1 = ((float)a2[2 * i + 1] - m2) * iv2 * gu.a[2 * i + 1] + bu.a[2 * i + 1];
            av1.v2[i] = pkrtz(x0, x1);
            av2.v2[i] = pkrtz(y0, y1);
        }
        *(f16x8*)(&As[buf][r1][c1]) = av1.v8;
        *(f16x8*)(&As[buf][r2][c2]) = av2.v8;
        *(f16x8*)(&Bs[buf][r1][c1]) = b1;
        *(f16x8*)(&Bs[buf][r2][c2]) = b2;
        __syncthreads();
        if (kt + 64 < DD) {
            a1 = *(const f16x8*)(y16 + (size_t)(n0 + r1) * DD + kt + 64 + c1);
            a2 = *(const f16x8*)(y16 + (size_t)(n0 + r2) * DD + kt + 64 + c2);
            b1 = *(const f16x8*)(Brow + (size_t)r1 * DD + kt + 64 + c1);
            b2 = *(const f16x8*)(Brow + (size_t)r2 * DD + kt + 64 + c2);
        }
        #pragma unroll
        for (int kk = 0; kk < 64; kk += 32) {
            f16x8 a = *(const f16x8*)(&As[buf][m0 + l16][kk + quad * 8]);
            #pragma unroll
            for (int t = 0; t < 4; ++t) {
                f16x8 b = *(const f16x8*)(&Bs[buf][t * 16 + l16][kk + quad * 8]);
                acc[t] = __builtin_amdgcn_mfma_f32_16x16x32_f16(a, b, acc[t], 0, 0, 0);
            }
        }
        buf ^= 1;
    }

    #pragma unroll
    for (int r = 0; r < 4; ++r) {
        const int row = n0 + m0 + quad * 4 + r;
        float ss = 0.f, qq = 0.f;
        #pragma unroll
        for (int jb = 0; jb < 8; ++jb) {
            ss += pstat[(size_t)jb * NN + row];
            qq += pstat[(size_t)(8 + jb) * NN + row];
        }
        const float mr = ss * (1.f / DD);
        const float ir = rsqrtf(qq * (1.f / DD) - mr * mr + 1e-5f);
        #pragma unroll
        for (int t = 0; t < 4; ++t) {
            const int col = j0 + t * 16 + l16;
            float nz = ((float)y16[(size_t)row * DD + col] - mr) * ir * lng[col] + lnb[col];
            float v = acc[t][r] + bias[col] + nz;
            out[(size_t)row * DD + col] = (f16)v;
        }
    }
}

// ---------------- row LayerNorm: y f16 [N][512] -> fp32 out ----------------
__global__ __launch_bounds__(256) void ln_kernel(
    const f16* __restrict__ y, const float* __restrict__ g, const float* __restrict__ b,
    float* __restrict__ of)
{
    const int lane = threadIdx.x & 63, wave = threadIdx.x >> 6;
    const int row = blockIdx.x * 4 + wave;
    f16x8 v = *(const f16x8*)(y + (size_t)row * DD + lane * 8);
    float vf[8];
    float s = 0.f, q = 0.f;
    #pragma unroll
    for (int i = 0; i < 8; ++i) {
        vf[i] = (float)v[i];
        s += vf[i];
        q += vf[i] * vf[i];
    }
    #pragma unroll
    for (int o = 1; o < 64; o <<= 1) { s += __shfl_xor(s, o); q += __shfl_xor(q, o); }
    float mean = s * (1.f / DD);
    float var = q * (1.f / DD) - mean * mean;
    float inv = rsqrtf(var + 1e-5f);

    f32x4 g0 = *(const f32x4*)(g + lane * 8);
    f32x4 g1 = *(const f32x4*)(g + lane * 8 + 4);
    f32x4 b0 = *(const f32x4*)(b + lane * 8);
    f32x4 b1 = *(const f32x4*)(b + lane * 8 + 4);
    f32x4 f0, f1;
    #pragma unroll
    for (int i = 0; i < 4; ++i) {
        f0[i] = (vf[i] - mean) * inv * g0[i] + b0[i];
        f1[i] = (vf[i + 4] - mean) * inv * g1[i] + b1[i];
    }
    *(f32x4*)(of + (size_t)row * DD + lane * 8) = f0;
    *(f32x4*)(of + (size_t)row * DD + lane * 8 + 4) = f1;
}

extern "C" void kernel_launch(void* const* d_in, const int* in_sizes, int n_in,
                              void* d_out, int out_size, void* d_ws, size_t ws_size,
                              hipStream_t stream) {
    const float* x     = (const float*)d_in[0];
    const float* wq    = (const float*)d_in[1];
    const float* wk    = (const float*)d_in[2];
    const float* wv    = (const float*)d_in[3];
    const float* w_mh  = (const float*)d_in[4];
    const float* ln1_g = (const float*)d_in[5];
    const float* ln1_b = (const float*)d_in[6];
    const float* ffn_w = (const float*)d_in[7];
    const float* ffn_b = (const float*)d_in[8];
    const float* ln2_g = (const float*)d_in[9];
    const float* ln2_b = (const float*)d_in[10];
    float* out = (float*)d_out;

    // persistent pool: weights + q/k/v + y16 + y2 + xh + pstat
    const size_t poolBytes = ((size_t)3 * HH * EE * DD + 2 * (size_t)DD * DD
                            + 3 * (size_t)HH * NN * EE + 3 * (size_t)NN * DD) * 2
                            + (size_t)16 * NN * 4;
    int SP = 2;
    {
        size_t need4 = (size_t)4 * NN * DD * 2 + (size_t)4 * HH * NN * 4 + poolBytes + 4096;
        if (ws_size >= need4) SP = 4;
    }

    // region A: Opart+lpart (live attn..gemmz)
    char* base = (char*)d_ws;
    f16* Opart = (f16*)base;                                        // SP*NN*DD f16
    float* lpart = (float*)(base + (size_t)SP * NN * DD * 2);       // SP*HH*NN f32
    size_t regionA = (size_t)SP * NN * DD * 2 + (size_t)SP * HH * NN * 4;
    regionA = (regionA + 255) & ~(size_t)255;
    f16* p = (f16*)(base + regionA);
    f16* wqkvT  = p; p += (size_t)3 * HH * EE * DD;           // [sel][h][e][d]
    f16* wmhT   = p; p += (size_t)DD * DD;                    // [j][k]
    f16* ffnT   = p; p += (size_t)DD * DD;                    // [j][k]
    f16* qh     = p; p += (size_t)HH * NN * EE;               // [h][n][e], scale baked
    f16* kh     = p; p += (size_t)HH * NN * EE;               // [h][n][e]
    f16* vTh    = p; p += (size_t)HH * NN * EE;               // [h][e][n]
    f16* y16    = p; p += (size_t)NN * DD;                    // gemmz out (pre-LN1)
    f16* y2     = p; p += (size_t)NN * DD;                    // gemmln2 out (pre-LN2)
    f16* xh     = p; p += (size_t)NN * DD;                    // persistent: gemmz residual
    float* pstat = (float*)p;                                 // [16][NN] partial row stats

    // prep (single launch)
    prep_kernel<<<dim3(256, 6), 256, 0, stream>>>(x, ffn_w, wq, wk, wv, w_mh,
                                                  xh, ffnT, wqkvT, wmhT);

    // main chain
    qkv_mfma_kernel<<<dim3(NN / 64, 24), 256, 0, stream>>>(xh, wqkvT, qh, kh, vTh);
    attn_mfma_kernel<<<dim3(HH, NN / BQ, SP), 256, 0, stream>>>(qh, kh, vTh, Opart, lpart);
    if (SP == 4)
        gemmz_mfma_kernel<4><<<dim3(NN / 64, DD / 64), 256, 0, stream>>>(Opart, lpart, wmhT, xh, y16, pstat);
    else
        gemmz_mfma_kernel<2><<<dim3(NN / 64, DD / 64), 256, 0, stream>>>(Opart, lpart, wmhT, xh, y16, pstat);
    gemmln2_kernel<<<dim3(NN / 64, DD / 64), 256, 0, stream>>>(y16, pstat, ffnT, ffn_b, ln1_g, ln1_b, y2);
    ln_kernel<<<dim3(NN / 4), 256, 0, stream>>>(y2, ln2_g, ln2_b, out);
}

// Round 17
// 176.785 us; speedup vs baseline: 1.0193x; 1.0193x over previous
//
#include <hip/hip_runtime.h>

#define NN 4096
#define DD 512
#define EE 64
#define HH 8

typedef _Float16 f16;
typedef f16 f16x2 __attribute__((ext_vector_type(2)));
typedef f16 f16x4 __attribute__((ext_vector_type(4)));
typedef f16 f16x8 __attribute__((ext_vector_type(8)));
typedef float f32x4 __attribute__((ext_vector_type(4)));
typedef __fp16 fp16x2 __attribute__((ext_vector_type(2)));

// hardware exp2 (v_exp_f32). NOTE: __exp2f collides with glibc math.h macros.
__device__ __forceinline__ float hexp2(float x) { return __builtin_amdgcn_exp2f(x); }
// packed f32x2 -> f16x2 (v_cvt_pkrtz_f16_f32); bit-cast fixes __fp16/_Float16 vec mismatch
__device__ __forceinline__ f16x2 pkrtz(float a, float b) {
    fp16x2 r = __builtin_amdgcn_cvt_pkrtz(a, b);
    return __builtin_bit_cast(f16x2, r);
}
// NOTE: clang forbids &vec[i] on ext_vector types — compose via unions.
union f16x4u { f16x4 v4; f16x2 v2[2]; };
union f16x8u { f16x8 v8; f16x2 v2[4]; };
union f32x8u { float a[8]; f32x4 v[2]; };

// ---------------- fused prep: converts + weight transposes, 1 launch ----------------
__device__ void tile_transpose_cvt(const float* __restrict__ src, f16* __restrict__ dst,
                                   int R, int C, int bx, int by, int tid)
{
    __shared__ float t[32][33];
    const int tx = tid & 31, ty = tid >> 5;
    #pragma unroll
    for (int i = 0; i < 4; ++i) {
        int r = ty + i * 8;
        t[r][tx] = src[(size_t)(by + r) * C + bx + tx];
    }
    __syncthreads();
    #pragma unroll
    for (int i = 0; i < 4; ++i) {
        int c = ty + i * 8;
        dst[(size_t)(bx + c) * R + by + tx] = (f16)t[tx][c];
    }
}

// grid (256, 6): y=0 x->f16 (8 passes), y=1 ffn_w->f16, y=2..4 wq/wk/wv transpose, y=5 w_mh transpose
__global__ __launch_bounds__(256) void prep_kernel(
    const float* __restrict__ x, const float* __restrict__ ffn_w,
    const float* __restrict__ wq, const float* __restrict__ wk, const float* __restrict__ wv,
    const float* __restrict__ w_mh,
    f16* __restrict__ xh, f16* __restrict__ ffnT, f16* __restrict__ wqkvT, f16* __restrict__ wmhT)
{
    const int job = blockIdx.y;
    const int tid = threadIdx.x;
    if (job == 0) {
        size_t i = ((size_t)blockIdx.x * 256 + tid) * 4;
        const size_t step = (size_t)256 * 256 * 4;
        for (; i < (size_t)NN * DD; i += step) {
            float4 t = *(const float4*)(x + i);
            f16x4 h = { (f16)t.x, (f16)t.y, (f16)t.z, (f16)t.w };
            *(f16x4*)(xh + i) = h;
        }
    } else if (job == 1) {
        size_t i = ((size_t)blockIdx.x * 256 + tid) * 4;   // DD*DD = 256 blocks exactly
        float4 t = *(const float4*)(ffn_w + i);
        f16x4 h = { (f16)t.x, (f16)t.y, (f16)t.z, (f16)t.w };
        *(f16x4*)(ffnT + i) = h;
    } else if (job <= 4) {
        const float* src = (job == 2) ? wq : (job == 3) ? wk : wv;
        f16* dst = wqkvT + (size_t)(job - 2) * HH * EE * DD;
        const int z = blockIdx.x >> 5;        // head 0..7
        const int tile = blockIdx.x & 31;     // 2 (E) x 16 (D)
        tile_transpose_cvt(src + (size_t)z * DD * EE, dst + (size_t)z * DD * EE,
                           DD, EE, (tile & 1) * 32, (tile >> 1) * 32, tid);
    } else {
        const int tile = blockIdx.x;          // 16 x 16
        tile_transpose_cvt(w_mh, wmhT, DD, DD, (tile & 15) * 32, (tile >> 4) * 32, tid);
    }
}

// ---------------- QKV GEMM v2: 128x64 tiles, K=512, single-buffer + reg prefetch ----------------
// grid (NN/128, 24): cb -> sel=cb>>3, h=cb&7. Each wave owns 32 rows x 64 cols:
// per-kt 16 MFMA vs 12 frag-reads + 6 staging stores (r16 tail analysis: old 64x64 tile
// was 8 MFMA per 14 LDS ops, 4 acc chains; this doubles MFMA:LDS ratio and ILP).
__global__ __launch_bounds__(256) void qkv_mfma_kernel(
    const f16* __restrict__ A, const f16* __restrict__ BT,
    f16* __restrict__ qh, f16* __restrict__ kh, f16* __restrict__ vTh)
{
    __shared__ f16 As[128][72];
    __shared__ f16 Bs[64][72];
    const int tid = threadIdx.x;
    const int n0 = blockIdx.x * 128;
    const int cb = blockIdx.y;
    const int sel = cb >> 3, h = cb & 7;
    const f16* Arow = A + (size_t)n0 * DD;
    const f16* Brow = BT + (size_t)cb * 64 * DD;

    const int lane = tid & 63, wave = tid >> 6;
    const int l16 = lane & 15, quad = lane >> 4;
    const int m0 = wave * 32;   // wave's 32-row strip

    f32x4 acc[2][4];
    #pragma unroll
    for (int i = 0; i < 2; ++i)
        #pragma unroll
        for (int t = 0; t < 4; ++t) acc[i][t] = (f32x4){0.f, 0.f, 0.f, 0.f};

    // register prefetch of first tile: A = 4 chunks/thread, B = 2 chunks/thread
    f16x8 ar[4], br[2];
    #pragma unroll
    for (int i = 0; i < 4; ++i) {
        int c = tid + i * 256;
        ar[i] = *(const f16x8*)(Arow + (size_t)(c >> 3) * DD + (c & 7) * 8);
    }
    #pragma unroll
    for (int i = 0; i < 2; ++i) {
        int c = tid + i * 256;
        br[i] = *(const f16x8*)(Brow + (size_t)(c >> 3) * DD + (c & 7) * 8);
    }

    for (int kt = 0; kt < DD; kt += 64) {
        __syncthreads();   // all waves done reading As/Bs from prev iter
        #pragma unroll
        for (int i = 0; i < 4; ++i) {
            int c = tid + i * 256;
            *(f16x8*)(&As[c >> 3][(c & 7) * 8]) = ar[i];
        }
        #pragma unroll
        for (int i = 0; i < 2; ++i) {
            int c = tid + i * 256;
            *(f16x8*)(&Bs[c >> 3][(c & 7) * 8]) = br[i];
        }
        __syncthreads();

        if (kt + 64 < DD) {   // prefetch next tile
            #pragma unroll
            for (int i = 0; i < 4; ++i) {
                int c = tid + i * 256;
                ar[i] = *(const f16x8*)(Arow + (size_t)(c >> 3) * DD + kt + 64 + (c & 7) * 8);
            }
            #pragma unroll
            for (int i = 0; i < 2; ++i) {
                int c = tid + i * 256;
                br[i] = *(const f16x8*)(Brow + (size_t)(c >> 3) * DD + kt + 64 + (c & 7) * 8);
            }
        }

        #pragma unroll
        for (int kk = 0; kk < 64; kk += 32) {
            f16x8 af0 = *(const f16x8*)(&As[m0 + l16][kk + quad * 8]);
            f16x8 af1 = *(const f16x8*)(&As[m0 + 16 + l16][kk + quad * 8]);
            #pragma unroll
            for (int t = 0; t < 4; ++t) {
                f16x8 b = *(const f16x8*)(&Bs[t * 16 + l16][kk + quad * 8]);
                acc[0][t] = __builtin_amdgcn_mfma_f32_16x16x32_f16(af0, b, acc[0][t], 0, 0, 0);
                acc[1][t] = __builtin_amdgcn_mfma_f32_16x16x32_f16(af1, b, acc[1][t], 0, 0, 0);
            }
        }
    }

    if (sel == 2) {
        #pragma unroll
        for (int i = 0; i < 2; ++i)
            #pragma unroll
            for (int t = 0; t < 4; ++t) {
                int e = t * 16 + l16;
                f16x4u v;
                v.v2[0] = pkrtz(acc[i][t][0], acc[i][t][1]);
                v.v2[1] = pkrtz(acc[i][t][2], acc[i][t][3]);
                *(f16x4*)(vTh + ((size_t)h * EE + e) * NN + n0 + m0 + i * 16 + quad * 4) = v.v4;
            }
    } else {
        f16* o = (sel == 0) ? qh : kh;
        // q: bake 1/sqrt(E) * log2(e) so attention can use raw v_exp_f32 (exp2)
        const float s = (sel == 0) ? 0.125f * 1.44269504088896f : 1.0f;
        #pragma unroll
        for (int i = 0; i < 2; ++i)
            #pragma unroll
            for (int r = 0; r < 4; ++r) {
                int row = n0 + m0 + i * 16 + quad * 4 + r;
                #pragma unroll
                for (int t = 0; t < 4; ++t)
                    o[(size_t)h * NN * EE + (size_t)row * EE + t * 16 + l16] = (f16)(acc[i][t][r] * s);
            }
    }
}

// ---------------- Flash attention (r15 config: BQ=128, 2 strips/wave — empirical optimum) ----------------
// r16 falsified wider strips (BQ=256: VGPR 132, occupancy 9.7%, dur +10%). BQ=128/SP=4/VGPR68
// is the saddle point of this structure. XCD-aware grid (h = blockIdx.x) keeps K/V in one L2.
#define BQ 128
#define NSTRIP 2
#define BK 64
#define LK (BK + 12)   // 76 halfs: frag-read row bank-step 6 mod 32 -> conflict-free

__global__ __launch_bounds__(256) void attn_mfma_kernel(
    const f16* __restrict__ q, const f16* __restrict__ k,
    const f16* __restrict__ vT, f16* __restrict__ Opart, float* __restrict__ lpart)
{
    __shared__ f16 Ks[BK][LK];    // permuted key rows
    __shared__ f16 VsT[EE][LK];   // [e][key]

    const int tid = threadIdx.x;
    const int h = blockIdx.x;               // XCD-locality dim
    const int n0 = blockIdx.y * BQ;
    const int sp = blockIdx.z;
    const int nsp = gridDim.z;
    const int wave = tid >> 6;
    const int lane = tid & 63;
    const int l16 = lane & 15;
    const int quad = lane >> 4;
    const int m0 = wave * 16;

    const f16* qh = q + (size_t)h * NN * EE;
    const f16* kh = k + (size_t)h * NN * EE;
    const f16* vh = vT + (size_t)h * NN * EE;  // [e][n]

    // Q B-fragments for all strips (loaded once from global)
    f16x8 qf[NSTRIP][2];
    #pragma unroll
    for (int s = 0; s < NSTRIP; ++s) {
        const f16* qb = qh + (size_t)(n0 + s * 64 + m0 + l16) * EE;
        qf[s][0] = *(const f16x8*)(qb + quad * 8);
        qf[s][1] = *(const f16x8*)(qb + 32 + quad * 8);
    }

    float lp[NSTRIP];
    f32x4 O[NSTRIP][4];
    #pragma unroll
    for (int s = 0; s < NSTRIP; ++s) {
        lp[s] = 0.f;
        #pragma unroll
        for (int t = 0; t < 4; ++t) O[s][t] = (f32x4){0.f, 0.f, 0.f, 0.f};
    }

    const int span = NN / nsp;
    const int k_begin = sp * span;
    const int k_end = k_begin + span;

    const int srow = tid >> 3, sc8 = (tid & 7) * 8;
    const int srow2 = (tid + 256) >> 3, sc82 = ((tid + 256) & 7) * 8;
    // key -> permuted LDS row: bits T,q,u,c -> T,u,q,c (verified r6)
    #define KPERM(kk_) (((kk_) & 0x23) | (((kk_) & 0x04) << 2) | (((kk_) & 0x18) >> 1))
    const int prow1 = KPERM(srow), prow2 = KPERM(srow2);

    // register prefetch of first tile
    f16x8 kr0 = *(const f16x8*)(kh + (size_t)(k_begin + srow) * EE + sc8);
    f16x8 kr1 = *(const f16x8*)(kh + (size_t)(k_begin + srow2) * EE + sc82);
    f16x8 vr0 = *(const f16x8*)(vh + (size_t)srow * NN + k_begin + sc8);
    f16x8 vr1 = *(const f16x8*)(vh + (size_t)srow2 * NN + k_begin + sc82);

    for (int kt = k_begin; kt < k_end; kt += BK) {
        __syncthreads();   // all waves done reading Ks/VsT from prev iter
        *(f16x8*)(&Ks[prow1][sc8]) = kr0;
        *(f16x8*)(&Ks[prow2][sc82]) = kr1;
        *(f16x8*)(&VsT[srow][sc8]) = vr0;
        *(f16x8*)(&VsT[srow2][sc82]) = vr1;
        __syncthreads();

        if (kt + BK < k_end) {   // prefetch next tile
            kr0 = *(const f16x8*)(kh + (size_t)(kt + BK + srow) * EE + sc8);
            kr1 = *(const f16x8*)(kh + (size_t)(kt + BK + srow2) * EE + sc82);
            vr0 = *(const f16x8*)(vh + (size_t)srow * NN + kt + BK + sc8);
            vr1 = *(const f16x8*)(vh + (size_t)srow2 * NN + kt + BK + sc82);
        }

        // S^T = K.Q^T per key-tile; each K-frag read feeds all strips
        f16x8 bf[NSTRIP][2];
        #pragma unroll
        for (int t = 0; t < 4; ++t) {
            f16x8 a0 = *(const f16x8*)(&Ks[t * 16 + l16][quad * 8]);
            f16x8 a1 = *(const f16x8*)(&Ks[t * 16 + l16][32 + quad * 8]);
            #pragma unroll
            for (int s = 0; s < NSTRIP; ++s) {
                f32x4 st = {0.f, 0.f, 0.f, 0.f};
                st = __builtin_amdgcn_mfma_f32_16x16x32_f16(a0, qf[s][0], st, 0, 0, 0);
                st = __builtin_amdgcn_mfma_f32_16x16x32_f16(a1, qf[s][1], st, 0, 0, 0);
                float p0 = hexp2(st[0]);
                float p1 = hexp2(st[1]);
                float p2 = hexp2(st[2]);
                float p3 = hexp2(st[3]);
                lp[s] += (p0 + p1) + (p2 + p3);
                f16x2* bp = (f16x2*)&bf[s][t >> 1];
                const int o2 = (t & 1) * 2;
                bp[o2 + 0] = pkrtz(p0, p1);
                bp[o2 + 1] = pkrtz(p2, p3);
            }
        }

        // O^T += V^T P^T ; each V-frag read feeds all strips
        #pragma unroll
        for (int te = 0; te < 4; ++te) {
            f16x8 v0 = *(const f16x8*)(&VsT[te * 16 + l16][quad * 8]);
            f16x8 v1 = *(const f16x8*)(&VsT[te * 16 + l16][32 + quad * 8]);
            #pragma unroll
            for (int s = 0; s < NSTRIP; ++s) {
                O[s][te] = __builtin_amdgcn_mfma_f32_16x16x32_f16(v0, bf[s][0], O[s][te], 0, 0, 0);
                O[s][te] = __builtin_amdgcn_mfma_f32_16x16x32_f16(v1, bf[s][1], O[s][te], 0, 0, 0);
            }
        }
    }

    // epilogue per strip: normalize by local l, store f16
    #pragma unroll
    for (int s = 0; s < NSTRIP; ++s) {
        float l = lp[s];
        l += __shfl_xor(l, 16);
        l += __shfl_xor(l, 32);
        const int row = n0 + s * 64 + m0 + l16;
        if (quad == 0)
            lpart[(size_t)sp * HH * NN + (size_t)h * NN + row] = l;
        const float inv = 1.f / l;
        f16* obase = Opart + ((size_t)sp * NN + row) * DD + h * EE;
        #pragma unroll
        for (int te = 0; te < 4; ++te) {
            f16x4u v;
            v.v2[0] = pkrtz(O[s][te][0] * inv, O[s][te][1] * inv);
            v.v2[1] = pkrtz(O[s][te][2] * inv, O[s][te][3] * inv);
            *(f16x4*)(obase + te * 16 + quad * 4) = v.v4;
        }
    }
}

// ---------------- GEMM1: fused split-combine in A-staging + row-stat emission ----------------
template<int NSP>
__global__ __launch_bounds__(256) void gemmz_mfma_kernel(
    const f16* __restrict__ Opart, const float* __restrict__ lpart,
    const f16* __restrict__ BT, const f16* __restrict__ resid16,
    f16* __restrict__ out, float* __restrict__ pstat)
{
    __shared__ f16 As[2][64][72];
    __shared__ f16 Bs[2][64][72];
    const int tid = threadIdx.x;
    const int n0 = blockIdx.x * 64;
    const int jb = blockIdx.y;
    const int j0 = jb * 64;
    const f16* Brow = BT + (size_t)j0 * DD;

    const int lane = tid & 63, wave = tid >> 6;
    const int l16 = lane & 15, quad = lane >> 4;
    const int m0 = wave * 16;

    const int r1 = tid >> 3, c1 = (tid & 7) * 8;
    const int r2 = (tid + 256) >> 3, c2 = ((tid + 256) & 7) * 8;

    f32x4 acc[4];
    #pragma unroll
    for (int t = 0; t < 4; ++t) acc[t] = (f32x4){0.f, 0.f, 0.f, 0.f};

    f16x8 op1[NSP], op2[NSP];
    #pragma unroll
    for (int s = 0; s < NSP; ++s) {
        op1[s] = *(const f16x8*)(Opart + ((size_t)s * NN + n0 + r1) * DD + c1);
        op2[s] = *(const f16x8*)(Opart + ((size_t)s * NN + n0 + r2) * DD + c2);
    }
    f16x8 b1 = *(const f16x8*)(Brow + (size_t)r1 * DD + c1);
    f16x8 b2 = *(const f16x8*)(Brow + (size_t)r2 * DD + c2);

    int buf = 0;
    for (int kt = 0; kt < DD; kt += 64) {
        const int h = kt >> 6;
        float lw1[NSP], lw2[NSP], s1 = 0.f, s2 = 0.f;
        #pragma unroll
        for (int s = 0; s < NSP; ++s) {
            lw1[s] = lpart[(size_t)s * HH * NN + (size_t)h * NN + n0 + r1];
            lw2[s] = lpart[(size_t)s * HH * NN + (size_t)h * NN + n0 + r2];
            s1 += lw1[s]; s2 += lw2[s];
        }
        const float i1 = 1.f / s1, i2 = 1.f / s2;
        float aw1[8], aw2[8];
        #pragma unroll
        for (int i = 0; i < 8; ++i) { aw1[i] = 0.f; aw2[i] = 0.f; }
        #pragma unroll
        for (int s = 0; s < NSP; ++s) {
            const float w1 = lw1[s] * i1, w2 = lw2[s] * i2;
            #pragma unroll
            for (int i = 0; i < 8; ++i) {
                aw1[i] += w1 * (float)op1[s][i];
                aw2[i] += w2 * (float)op2[s][i];
            }
        }
        f16x8u av1, av2;
        #pragma unroll
        for (int i = 0; i < 4; ++i) {
            av1.v2[i] = pkrtz(aw1[2 * i], aw1[2 * i + 1]);
            av2.v2[i] = pkrtz(aw2[2 * i], aw2[2 * i + 1]);
        }
        *(f16x8*)(&As[buf][r1][c1]) = av1.v8;
        *(f16x8*)(&As[buf][r2][c2]) = av2.v8;
        *(f16x8*)(&Bs[buf][r1][c1]) = b1;
        *(f16x8*)(&Bs[buf][r2][c2]) = b2;
        __syncthreads();
        if (kt + 64 < DD) {
            #pragma unroll
            for (int s = 0; s < NSP; ++s) {
                op1[s] = *(const f16x8*)(Opart + ((size_t)s * NN + n0 + r1) * DD + kt + 64 + c1);
                op2[s] = *(const f16x8*)(Opart + ((size_t)s * NN + n0 + r2) * DD + kt + 64 + c2);
            }
            b1 = *(const f16x8*)(Brow + (size_t)r1 * DD + kt + 64 + c1);
            b2 = *(const f16x8*)(Brow + (size_t)r2 * DD + kt + 64 + c2);
        }
        #pragma unroll
        for (int kk = 0; kk < 64; kk += 32) {
            f16x8 a = *(const f16x8*)(&As[buf][m0 + l16][kk + quad * 8]);
            #pragma unroll
            for (int t = 0; t < 4; ++t) {
                f16x8 b = *(const f16x8*)(&Bs[buf][t * 16 + l16][kk + quad * 8]);
                acc[t] = __builtin_amdgcn_mfma_f32_16x16x32_f16(a, b, acc[t], 0, 0, 0);
            }
        }
        buf ^= 1;
    }

    float vv[4][4];   // [r][t]
    #pragma unroll
    for (int r = 0; r < 4; ++r) {
        int row = n0 + m0 + quad * 4 + r;
        #pragma unroll
        for (int t = 0; t < 4; ++t) {
            int col = j0 + t * 16 + l16;
            float v = acc[t][r] + (float)resid16[(size_t)row * DD + col];
            vv[r][t] = v;
            out[(size_t)row * DD + col] = (f16)v;
        }
    }
    #pragma unroll
    for (int r = 0; r < 4; ++r) {
        float s = (vv[r][0] + vv[r][1]) + (vv[r][2] + vv[r][3]);
        float q = (vv[r][0] * vv[r][0] + vv[r][1] * vv[r][1])
                + (vv[r][2] * vv[r][2] + vv[r][3] * vv[r][3]);
        s += __shfl_xor(s, 1); q += __shfl_xor(q, 1);
        s += __shfl_xor(s, 2); q += __shfl_xor(q, 2);
        s += __shfl_xor(s, 4); q += __shfl_xor(q, 4);
        s += __shfl_xor(s, 8); q += __shfl_xor(q, 8);
        if (l16 == 0) {
            int row = n0 + m0 + quad * 4 + r;
            pstat[(size_t)jb * NN + row] = s;
            pstat[(size_t)(8 + jb) * NN + row] = q;
        }
    }
}

// ---------------- GEMM2 with LN1 fused into A-staging + residual epilogue ----------------
__global__ __launch_bounds__(256) void gemmln2_kernel(
    const f16* __restrict__ y16, const float* __restrict__ pstat,
    const f16* __restrict__ BT, const float* __restrict__ bias,
    const float* __restrict__ lng, const float* __restrict__ lnb,
    f16* __restrict__ out)
{
    __shared__ f16 As[2][64][72];
    __shared__ f16 Bs[2][64][72];
    const int tid = threadIdx.x;
    const int n0 = blockIdx.x * 64;
    const int j0 = blockIdx.y * 64;
    const f16* Brow = BT + (size_t)j0 * DD;

    const int lane = tid & 63, wave = tid >> 6;
    const int l16 = lane & 15, quad = lane >> 4;
    const int m0 = wave * 16;

    const int r1 = tid >> 3, c1 = (tid & 7) * 8;
    const int r2 = (tid + 256) >> 3, c2 = ((tid + 256) & 7) * 8;

    float s1 = 0.f, q1 = 0.f, s2 = 0.f, q2 = 0.f;
    #pragma unroll
    for (int jb = 0; jb < 8; ++jb) {
        s1 += pstat[(size_t)jb * NN + n0 + r1];
        q1 += pstat[(size_t)(8 + jb) * NN + n0 + r1];
        s2 += pstat[(size_t)jb * NN + n0 + r2];
        q2 += pstat[(size_t)(8 + jb) * NN + n0 + r2];
    }
    const float m1 = s1 * (1.f / DD), m2 = s2 * (1.f / DD);
    const float iv1 = rsqrtf(q1 * (1.f / DD) - m1 * m1 + 1e-5f);
    const float iv2 = rsqrtf(q2 * (1.f / DD) - m2 * m2 + 1e-5f);

    f32x4 acc[4];
    #pragma unroll
    for (int t = 0; t < 4; ++t) acc[t] = (f32x4){0.f, 0.f, 0.f, 0.f};

    f16x8 a1 = *(const f16x8*)(y16 + (size_t)(n0 + r1) * DD + c1);
    f16x8 a2 = *(const f16x8*)(y16 + (size_t)(n0 + r2) * DD + c2);
    f16x8 b1 = *(const f16x8*)(Brow + (size_t)r1 * DD + c1);
    f16x8 b2 = *(const f16x8*)(Brow + (size_t)r2 * DD + c2);

    int buf = 0;
    for (int kt = 0; kt < DD; kt += 64) {
        f32x8u gu, bu;
        gu.v[0] = *(const f32x4*)(lng + kt + c1);
        gu.v[1] = *(const f32x4*)(lng + kt + c1 + 4);
        bu.v[0] = *(const f32x4*)(lnb + kt + c1);
        bu.v[1] = *(const f32x4*)(lnb + kt + c1 + 4);
        f16x8u av1, av2;
        #pragma unroll
        for (int i = 0; i < 4; ++i) {
            float x0 = ((float)a1[2 * i]     - m1) * iv1 * gu.a[2 * i]     + bu.a[2 * i];
            float x1 = ((float)a1[2 * i + 1] - m1) * iv1 * gu.a[2 * i + 1] + bu.a[2 * i + 1];
            float y0 = ((float)a2[2 * i]     - m2) * iv2 * gu.a[2 * i]     + bu.a[2 * i];
            float y1 = ((float)a2[2 * i + 1] - m2) * iv2 * gu.a[2 * i + 1] + bu.a[2 * i + 1];
            av1.v2[i] = pkrtz(x0, x1);
            av2.v2[i] = pkrtz(y0, y1);
        }
        *(f16x8*)(&As[buf][r1][c1]) = av1.v8;
        *(f16x8*)(&As[buf][r2][c2]) = av2.v8;
        *(f16x8*)(&Bs[buf][r1][c1]) = b1;
        *(f16x8*)(&Bs[buf][r2][c2]) = b2;
        __syncthreads();
        if (kt + 64 < DD) {
            a1 = *(const f16x8*)(y16 + (size_t)(n0 + r1) * DD + kt + 64 + c1);
            a2 = *(const f16x8*)(y16 + (size_t)(n0 + r2) * DD + kt + 64 + c2);
            b1 = *(const f16x8*)(Brow + (size_t)r1 * DD + kt + 64 + c1);
            b2 = *(const f16x8*)(Brow + (size_t)r2 * DD + kt + 64 + c2);
        }
        #pragma unroll
        for (int kk = 0; kk < 64; kk += 32) {
            f16x8 a = *(const f16x8*)(&As[buf][m0 + l16][kk + quad * 8]);
            #pragma unroll
            for (int t = 0; t < 4; ++t) {
                f16x8 b = *(const f16x8*)(&Bs[buf][t * 16 + l16][kk + quad * 8]);
                acc[t] = __builtin_amdgcn_mfma_f32_16x16x32_f16(a, b, acc[t], 0, 0, 0);
            }
        }
        buf ^= 1;
    }

    #pragma unroll
    for (int r = 0; r < 4; ++r) {
        const int row = n0 + m0 + quad * 4 + r;
        float ss = 0.f, qq = 0.f;
        #pragma unroll
        for (int jb = 0; jb < 8; ++jb) {
            ss += pstat[(size_t)jb * NN + row];
            qq += pstat[(size_t)(8 + jb) * NN + row];
        }
        const float mr = ss * (1.f / DD);
        const float ir = rsqrtf(qq * (1.f / DD) - mr * mr + 1e-5f);
        #pragma unroll
        for (int t = 0; t < 4; ++t) {
            const int col = j0 + t * 16 + l16;
            float nz = ((float)y16[(size_t)row * DD + col] - mr) * ir * lng[col] + lnb[col];
            float v = acc[t][r] + bias[col] + nz;
            out[(size_t)row * DD + col] = (f16)v;
        }
    }
}

// ---------------- row LayerNorm: y f16 [N][512] -> fp32 out ----------------
__global__ __launch_bounds__(256) void ln_kernel(
    const f16* __restrict__ y, const float* __restrict__ g, const float* __restrict__ b,
    float* __restrict__ of)
{
    const int lane = threadIdx.x & 63, wave = threadIdx.x >> 6;
    const int row = blockIdx.x * 4 + wave;
    f16x8 v = *(const f16x8*)(y + (size_t)row * DD + lane * 8);
    float vf[8];
    float s = 0.f, q = 0.f;
    #pragma unroll
    for (int i = 0; i < 8; ++i) {
        vf[i] = (float)v[i];
        s += vf[i];
        q += vf[i] * vf[i];
    }
    #pragma unroll
    for (int o = 1; o < 64; o <<= 1) { s += __shfl_xor(s, o); q += __shfl_xor(q, o); }
    float mean = s * (1.f / DD);
    float var = q * (1.f / DD) - mean * mean;
    float inv = rsqrtf(var + 1e-5f);

    f32x4 g0 = *(const f32x4*)(g + lane * 8);
    f32x4 g1 = *(const f32x4*)(g + lane * 8 + 4);
    f32x4 b0 = *(const f32x4*)(b + lane * 8);
    f32x4 b1 = *(const f32x4*)(b + lane * 8 + 4);
    f32x4 f0, f1;
    #pragma unroll
    for (int i = 0; i < 4; ++i) {
        f0[i] = (vf[i] - mean) * inv * g0[i] + b0[i];
        f1[i] = (vf[i + 4] - mean) * inv * g1[i] + b1[i];
    }
    *(f32x4*)(of + (size_t)row * DD + lane * 8) = f0;
    *(f32x4*)(of + (size_t)row * DD + lane * 8 + 4) = f1;
}

extern "C" void kernel_launch(void* const* d_in, const int* in_sizes, int n_in,
                              void* d_out, int out_size, void* d_ws, size_t ws_size,
                              hipStream_t stream) {
    const float* x     = (const float*)d_in[0];
    const float* wq    = (const float*)d_in[1];
    const float* wk    = (const float*)d_in[2];
    const float* wv    = (const float*)d_in[3];
    const float* w_mh  = (const float*)d_in[4];
    const float* ln1_g = (const float*)d_in[5];
    const float* ln1_b = (const float*)d_in[6];
    const float* ffn_w = (const float*)d_in[7];
    const float* ffn_b = (const float*)d_in[8];
    const float* ln2_g = (const float*)d_in[9];
    const float* ln2_b = (const float*)d_in[10];
    float* out = (float*)d_out;

    // persistent pool: weights + q/k/v + y16 + y2 + xh + pstat
    const size_t poolBytes = ((size_t)3 * HH * EE * DD + 2 * (size_t)DD * DD
                            + 3 * (size_t)HH * NN * EE + 3 * (size_t)NN * DD) * 2
                            + (size_t)16 * NN * 4;
    int SP = 2;
    {
        size_t need4 = (size_t)4 * NN * DD * 2 + (size_t)4 * HH * NN * 4 + poolBytes + 4096;
        if (ws_size >= need4) SP = 4;
    }

    // region A: Opart+lpart (live attn..gemmz)
    char* base = (char*)d_ws;
    f16* Opart = (f16*)base;                                        // SP*NN*DD f16
    float* lpart = (float*)(base + (size_t)SP * NN * DD * 2);       // SP*HH*NN f32
    size_t regionA = (size_t)SP * NN * DD * 2 + (size_t)SP * HH * NN * 4;
    regionA = (regionA + 255) & ~(size_t)255;
    f16* p = (f16*)(base + regionA);
    f16* wqkvT  = p; p += (size_t)3 * HH * EE * DD;           // [sel][h][e][d]
    f16* wmhT   = p; p += (size_t)DD * DD;                    // [j][k]
    f16* ffnT   = p; p += (size_t)DD * DD;                    // [j][k]
    f16* qh     = p; p += (size_t)HH * NN * EE;               // [h][n][e], scale baked
    f16* kh     = p; p += (size_t)HH * NN * EE;               // [h][n][e]
    f16* vTh    = p; p += (size_t)HH * NN * EE;               // [h][e][n]
    f16* y16    = p; p += (size_t)NN * DD;                    // gemmz out (pre-LN1)
    f16* y2     = p; p += (size_t)NN * DD;                    // gemmln2 out (pre-LN2)
    f16* xh     = p; p += (size_t)NN * DD;                    // persistent: gemmz residual
    float* pstat = (float*)p;                                 // [16][NN] partial row stats

    // prep (single launch)
    prep_kernel<<<dim3(256, 6), 256, 0, stream>>>(x, ffn_w, wq, wk, wv, w_mh,
                                                  xh, ffnT, wqkvT, wmhT);

    // main chain
    qkv_mfma_kernel<<<dim3(NN / 128, 24), 256, 0, stream>>>(xh, wqkvT, qh, kh, vTh);
    attn_mfma_kernel<<<dim3(HH, NN / BQ, SP), 256, 0, stream>>>(qh, kh, vTh, Opart, lpart);
    if (SP == 4)
        gemmz_mfma_kernel<4><<<dim3(NN / 64, DD / 64), 256, 0, stream>>>(Opart, lpart, wmhT, xh, y16, pstat);
    else
        gemmz_mfma_kernel<2><<<dim3(NN / 64, DD / 64), 256, 0, stream>>>(Opart, lpart, wmhT, xh, y16, pstat);
    gemmln2_kernel<<<dim3(NN / 64, DD / 64), 256, 0, stream>>>(y16, pstat, ffnT, ffn_b, ln1_g, ln1_b, y2);
    ln_kernel<<<dim3(NN / 4), 256, 0, stream>>>(y2, ln2_g, ln2_b, out);
}